// Round 4
// baseline (804.503 us; speedup 1.0000x reference)
//
// SGBlock fused forward, MI355X (gfx950).
// R3: GEMM depth-4 ring + counted vmcnt (T4) + raw s_barrier; k_token_a -> thin
//     MFMA GEMM (k_lin) with qkv folded into k_attn; k_token_c vectorized.
#include <hip/hip_runtime.h>
#include <hip/hip_bf16.h>

typedef unsigned short u16;
typedef __bf16 bf16x8 __attribute__((ext_vector_type(8)));
typedef float f32x4 __attribute__((ext_vector_type(4)));

#define B_    128
#define N_TOK 320
#define D_    768
#define M_TOT (B_ * N_TOK)   // 40960

// ---------------- helpers ----------------
__device__ __forceinline__ u16 f2b(float x) {
  __hip_bfloat16 t = __float2bfloat16(x);
  return *reinterpret_cast<u16*>(&t);
}

typedef const __attribute__((address_space(1))) void* gas1_t;
typedef __attribute__((address_space(3))) void* las3_t;
__device__ __forceinline__ void gll16(const void* g, void* l) {
  __builtin_amdgcn_global_load_lds((gas1_t)g, (las3_t)l, 16, 0, 0);
}

#define RAW_BARRIER() asm volatile("s_barrier" ::: "memory")

// two-value block reduction over 256 threads (4 waves)
__device__ __forceinline__ void block_reduce2(float& a, float& b, float* red, int t) {
  #pragma unroll
  for (int off = 32; off >= 1; off >>= 1) {
    a += __shfl_xor(a, off);
    b += __shfl_xor(b, off);
  }
  int wv = t >> 6;
  __syncthreads();
  if ((t & 63) == 0) { red[wv] = a; red[4 + wv] = b; }
  __syncthreads();
  a = red[0] + red[1] + red[2] + red[3];
  b = red[4] + red[5] + red[6] + red[7];
}

// ---------------- 1: weight transpose fp32[K][N] -> bf16[N][K] ----------------
__global__ __launch_bounds__(256) void k_transpose_bf16(const float* __restrict__ in,
                                                        u16* __restrict__ out) {
  __shared__ float tile[32][33];
  int c0 = blockIdx.x * 32, r0 = blockIdx.y * 32;
  int tx = threadIdx.x, ty = threadIdx.y;
  #pragma unroll
  for (int k = 0; k < 4; k++)
    tile[ty + k * 8][tx] = in[(size_t)(r0 + ty + k * 8) * 768 + c0 + tx];
  __syncthreads();
  #pragma unroll
  for (int k = 0; k < 4; k++)
    out[(size_t)(c0 + ty + k * 8) * 768 + r0 + tx] = f2b(tile[tx][ty + k * 8]);
}

// ---------------- 2: k_lin — yxa[tok][16] = x @ [lin_w | ad_w] (+bias, relu on y) ----
// MFMA 16x16x32: A = x rows (fp32->bf16 in reg), B = Wt[16][768] resident in LDS.
__global__ __launch_bounds__(256) void k_lin(
    const float* __restrict__ x,
    const float* __restrict__ lin_w, const float* __restrict__ lin_b,
    const float* __restrict__ ad_w, const float* __restrict__ ad_b,
    float* __restrict__ yxa) {
  __shared__ __align__(16) u16 Wt[16 * 776];   // padded rows: 776 elems = 1552 B
  int t = threadIdx.x;
  #pragma unroll 4
  for (int r = 0; r < 48; r++) {
    int i = r * 256 + t;
    int j = i / 768, k = i - j * 768;
    float w = (j < 8) ? lin_w[k * 8 + j] : ad_w[k * 8 + (j - 8)];
    Wt[j * 776 + k] = f2b(w);
  }
  __syncthreads();
  int wave = t >> 6, lane = t & 63, l15 = lane & 15, l4 = lane >> 4;
  int m0 = blockIdx.x * 64 + wave * 16;
  const float* xrow = x + (size_t)(m0 + l15) * 768 + l4 * 8;
  f32x4 acc = {0.f, 0.f, 0.f, 0.f};
  union BF8 { bf16x8 v; u16 s[8]; };
  float4 c0 = *reinterpret_cast<const float4*>(xrow);
  float4 c1 = *reinterpret_cast<const float4*>(xrow + 4);
  #pragma unroll
  for (int k = 0; k < 24; k++) {
    float4 n0, n1;
    if (k < 23) {
      n0 = *reinterpret_cast<const float4*>(xrow + (k + 1) * 32);
      n1 = *reinterpret_cast<const float4*>(xrow + (k + 1) * 32 + 4);
    }
    BF8 af;
    af.s[0] = f2b(c0.x); af.s[1] = f2b(c0.y); af.s[2] = f2b(c0.z); af.s[3] = f2b(c0.w);
    af.s[4] = f2b(c1.x); af.s[5] = f2b(c1.y); af.s[6] = f2b(c1.z); af.s[7] = f2b(c1.w);
    bf16x8 wfrag = *reinterpret_cast<const bf16x8*>(&Wt[l15 * 776 + k * 32 + l4 * 8]);
    acc = __builtin_amdgcn_mfma_f32_16x16x32_bf16(af.v, wfrag, acc, 0, 0, 0);
    c0 = n0; c1 = n1;
  }
  // C/D: col j = l15, row = l4*4 + rg
  int j = l15;
  float bias = (j < 8) ? lin_b[j] : ad_b[j - 8];
  #pragma unroll
  for (int rg = 0; rg < 4; rg++) {
    int tok = m0 + l4 * 4 + rg;
    float v = acc[rg] + bias;
    if (j < 8) v = fmaxf(v, 0.f);
    yxa[(size_t)tok * 16 + j] = v;
  }
}

// ---------------- 3: attention (dh=1), qkv computed inline from yxa ----------------
__global__ __launch_bounds__(320) void k_attn(
    const float* __restrict__ yxa, const float* __restrict__ qkv_w,
    const float* __restrict__ qkv_b, float* __restrict__ av) {
  __shared__ float ks[320], vs[320];
  __shared__ float red[12];
  int bh = blockIdx.x, b_ = bh >> 3, h_ = bh & 7;
  int n = threadIdx.x;          // 0..319
  const float* yr = yxa + ((size_t)b_ * 320 + n) * 16;
  float4 y0 = *reinterpret_cast<const float4*>(yr);
  float4 y1 = *reinterpret_cast<const float4*>(yr + 4);
  float yv[8] = {y0.x, y0.y, y0.z, y0.w, y1.x, y1.y, y1.z, y1.w};
  float qn = qkv_b[h_], kk = qkv_b[8 + h_], vv = qkv_b[16 + h_];
  #pragma unroll
  for (int j = 0; j < 8; j++) {
    qn += yv[j] * qkv_w[j * 24 + h_];
    kk += yv[j] * qkv_w[j * 24 + 8 + h_];
    vv += yv[j] * qkv_w[j * 24 + 16 + h_];
  }
  ks[n] = kk;
  vs[n] = vv;
  float mx = kk, mn = kk;
  #pragma unroll
  for (int off = 32; off >= 1; off >>= 1) {
    mx = fmaxf(mx, __shfl_xor(mx, off));
    mn = fminf(mn, __shfl_xor(mn, off));
  }
  int wave = n >> 6;
  if ((n & 63) == 0) { red[wave] = mx; red[5 + wave] = mn; }
  __syncthreads();
  if (n == 0) {
    float a = red[0], b = red[5];
    #pragma unroll
    for (int w = 1; w < 5; w++) { a = fmaxf(a, red[w]); b = fminf(b, red[5 + w]); }
    red[10] = a; red[11] = b;
  }
  __syncthreads();
  float kmax = red[10], kmin = red[11];
  float m1 = fmaxf(qn * kmax, qn * kmin);
  float se = 0.f, sv = 0.f;
  for (int m = 0; m < 320; m++) {
    float e = __expf(qn * ks[m] - m1);
    se += e;
    sv += e * vs[m];
  }
  av[(((size_t)b_ * 320) + n) * 8 + h_] = sv / se;
}

// ---------------- 4: residual + LN + LN2 -> h (bf16), vectorized ----------------
__global__ __launch_bounds__(256) void k_token_c(
    const float* __restrict__ x, const float* __restrict__ yxa, const float* __restrict__ av_ws,
    const float* __restrict__ proj_w, const float* __restrict__ proj_b,
    const float* __restrict__ end_w, const float* __restrict__ end_b,
    const float* __restrict__ g1ln, const float* __restrict__ b1ln,
    const float* __restrict__ g2ln, const float* __restrict__ b2ln,
    u16* __restrict__ hout) {
  __shared__ float red[8];
  size_t tok = blockIdx.x;
  int t = threadIdx.x;
  float u[8];
  #pragma unroll
  for (int o = 0; o < 8; o++) {
    float a = proj_b[o];
    #pragma unroll
    for (int j = 0; j < 8; j++) a += av_ws[tok * 8 + j] * proj_w[j * 8 + o];
    u[o] = a + yxa[tok * 16 + o];
  }
  const bool act = t < 192;
  const int d0 = t * 4;
  float tv[4] = {0.f, 0.f, 0.f, 0.f};
  if (act) {
    float4 xv = *reinterpret_cast<const float4*>(x + tok * 768 + d0);
    float4 bv = *reinterpret_cast<const float4*>(end_b + d0);
    tv[0] = xv.x + bv.x; tv[1] = xv.y + bv.y; tv[2] = xv.z + bv.z; tv[3] = xv.w + bv.w;
    #pragma unroll
    for (int j = 0; j < 8; j++) {
      float4 wv = *reinterpret_cast<const float4*>(end_w + j * 768 + d0);
      tv[0] += u[j] * wv.x; tv[1] += u[j] * wv.y;
      tv[2] += u[j] * wv.z; tv[3] += u[j] * wv.w;
    }
  }
  float s = tv[0] + tv[1] + tv[2] + tv[3];
  float s2 = tv[0] * tv[0] + tv[1] * tv[1] + tv[2] * tv[2] + tv[3] * tv[3];
  block_reduce2(s, s2, red, t);
  float m1 = s * (1.f / 768.f);
  float inv1 = rsqrtf(fmaxf(s2 * (1.f / 768.f) - m1 * m1, 0.f) + 1e-5f);
  float x0[4];
  float sb = 0.f, sb2 = 0.f;
  if (act) {
    float4 g1 = *reinterpret_cast<const float4*>(g1ln + d0);
    float4 bb1 = *reinterpret_cast<const float4*>(b1ln + d0);
    x0[0] = (tv[0] - m1) * inv1 * g1.x + bb1.x;
    x0[1] = (tv[1] - m1) * inv1 * g1.y + bb1.y;
    x0[2] = (tv[2] - m1) * inv1 * g1.z + bb1.z;
    x0[3] = (tv[3] - m1) * inv1 * g1.w + bb1.w;
    sb = x0[0] + x0[1] + x0[2] + x0[3];
    sb2 = x0[0] * x0[0] + x0[1] * x0[1] + x0[2] * x0[2] + x0[3] * x0[3];
  }
  block_reduce2(sb, sb2, red, t);
  float m2 = sb * (1.f / 768.f);
  float inv2 = rsqrtf(fmaxf(sb2 * (1.f / 768.f) - m2 * m2, 0.f) + 1e-5f);
  if (act) {
    float4 g2 = *reinterpret_cast<const float4*>(g2ln + d0);
    float4 bb2 = *reinterpret_cast<const float4*>(b2ln + d0);
    short4 hv;
    hv.x = (short)f2b((x0[0] - m2) * inv2 * g2.x + bb2.x);
    hv.y = (short)f2b((x0[1] - m2) * inv2 * g2.y + bb2.y);
    hv.z = (short)f2b((x0[2] - m2) * inv2 * g2.z + bb2.z);
    hv.w = (short)f2b((x0[3] - m2) * inv2 * g2.w + bb2.w);
    *reinterpret_cast<short4*>(hout + tok * 768 + d0) = hv;
  }
}

// ---------------- 5/6: adapter branch (conv1x1+bn+relu, SGN via direct DFT, convs, bns) ----------------
template <int S>
__global__ __launch_bounds__(256) void k_adapter(
    const float* __restrict__ yxa,
    const float* __restrict__ bw, const float* __restrict__ bb,
    const float* __restrict__ bng0, const float* __restrict__ bnb0,
    const float* __restrict__ cw,
    const float* __restrict__ crw, const float* __restrict__ crb,
    const float* __restrict__ ciw, const float* __restrict__ cib,
    const float* __restrict__ bn1g, const float* __restrict__ bn1b,
    const float* __restrict__ bn2g, const float* __restrict__ bn2b,
    const float* __restrict__ cvw, const float* __restrict__ cvb,
    const float* __restrict__ c3w, const float* __restrict__ c3b,
    const float* __restrict__ bng, const float* __restrict__ bnb,
    float* __restrict__ crout, int tok_off) {
  constexpr int NF = S / 2 + 1;
  constexpr int P = S * S;
  constexpr int NFREQ = S * NF * 8;
  __shared__ float xr[8 * P];
  __shared__ float x1[8 * P];
  __shared__ float xo[8 * P];
  __shared__ float bufA[NFREQ * 2];
  __shared__ float bufB[NFREQ * 2];
  __shared__ float cosT[S], sinT[S];
  const int b = blockIdx.x, t = threadIdx.x;
  const float binv = rsqrtf(1.f + 1e-5f);
  if (t < S) {
    float ang = 6.28318530717958647692f * (float)t / (float)S;
    cosT[t] = cosf(ang);
    sinT[t] = sinf(ang);
  }
  for (int i = t; i < 8 * P; i += 256) {
    int c = i / P, p = i % P;
    xr[i] = yxa[((size_t)b * N_TOK + tok_off + p) * 16 + 8 + c];
  }
  __syncthreads();
  for (int i = t; i < 8 * P; i += 256) {
    int c = i / P, p = i % P;
    float a = bb[c];
    #pragma unroll
    for (int j = 0; j < 8; j++) a += xr[j * P + p] * bw[c * 8 + j];
    a = a * (bng0[c] * binv) + bnb0[c];
    x1[i] = fmaxf(a, 0.f);
  }
  __syncthreads();
  for (int i = t; i < NFREQ; i += 256) {
    int c = i & 7, v = (i >> 3) % NF, w = i / (8 * NF);
    float re = 0.f, im = 0.f;
    #pragma unroll
    for (int h = 0; h < S; h++) {
      float xv = x1[c * P + h * S + w];
      int idx = (v * h) % S;
      re += xv * cosT[idx];
      im -= xv * sinT[idx];
    }
    bufA[i * 2] = re;
    bufA[i * 2 + 1] = im;
  }
  __syncthreads();
  for (int i = t; i < NFREQ; i += 256) {
    int c = i & 7, v = (i >> 3) % NF, u = i / (8 * NF);
    float re = 0.f, im = 0.f;
    #pragma unroll
    for (int w = 0; w < S; w++) {
      float ar = bufA[((w * NF + v) * 8 + c) * 2];
      float ai = bufA[((w * NF + v) * 8 + c) * 2 + 1];
      int idx = (u * w) % S;
      float cs = cosT[idx], sn = sinT[idx];
      re += ar * cs + ai * sn;
      im += ai * cs - ar * sn;
    }
    bufB[i * 2] = re * (1.f / S);
    bufB[i * 2 + 1] = im * (1.f / S);
  }
  __syncthreads();
  for (int i = t; i < NFREQ; i += 256) {
    int c = i & 7;
    int uv = i >> 3;
    float fr = crb[c], fi = cib[c];
    #pragma unroll
    for (int j = 0; j < 8; j++) {
      fr += bufB[(uv * 8 + j) * 2] * crw[c * 8 + j];
      fi += bufB[(uv * 8 + j) * 2 + 1] * ciw[c * 8 + j];
    }
    fr = fmaxf(fr * (bn1g[c] * binv) + bn1b[c], 0.f);
    fi = fmaxf(fi * (bn2g[c] * binv) + bn2b[c], 0.f);
    float cwr = cw[i * 2], cwi = cw[i * 2 + 1];
    bufA[i * 2] = fr * cwr - fi * cwi;
    bufA[i * 2 + 1] = fr * cwi + fi * cwr;
  }
  __syncthreads();
  for (int i = t; i < NFREQ; i += 256) {
    int c = i & 7, v = (i >> 3) % NF, w = i / (8 * NF);
    float re = 0.f, im = 0.f;
    #pragma unroll
    for (int u = 0; u < S; u++) {
      float gr = bufA[((u * NF + v) * 8 + c) * 2];
      float gi = bufA[((u * NF + v) * 8 + c) * 2 + 1];
      int idx = (u * w) % S;
      float cs = cosT[idx], sn = sinT[idx];
      re += gr * cs - gi * sn;
      im += gi * cs + gr * sn;
    }
    bufB[((w * NF + v) * 8 + c) * 2] = re;
    bufB[((w * NF + v) * 8 + c) * 2 + 1] = im;
  }
  __syncthreads();
  for (int i = t; i < 8 * P; i += 256) {
    int c = i / P, p = i % P, h = p / S, w = p % S;
    float acc = bufB[((w * NF + 0) * 8 + c) * 2];
    float ny = bufB[((w * NF + (NF - 1)) * 8 + c) * 2];
    acc += (h & 1) ? -ny : ny;
    #pragma unroll
    for (int v = 1; v < NF - 1; v++) {
      int idx = (v * h) % S;
      acc += 2.f * (bufB[((w * NF + v) * 8 + c) * 2] * cosT[idx] -
                    bufB[((w * NF + v) * 8 + c) * 2 + 1] * sinT[idx]);
    }
    xo[i] = acc * (1.f / S) + x1[i];
  }
  __syncthreads();
  for (int i = t; i < 8 * P; i += 256) {
    int c = i / P, p = i % P, h = p / S, w = p % S;
    float a = cvb[c];
    #pragma unroll
    for (int j = 0; j < 8; j++) a += xo[j * P + p] * cvw[c * 8 + j];
    a = fmaxf(a * (bng[c] * binv) + bnb[c], 0.f);
    float x2 = c3b[c];
    #pragma unroll
    for (int j = 0; j < 8; j++) {
      #pragma unroll
      for (int dy = 0; dy < 3; dy++) {
        int hh = h + dy - 1;
        if (hh < 0 || hh >= S) continue;
        #pragma unroll
        for (int dx = 0; dx < 3; dx++) {
          int ww = w + dx - 1;
          if (ww < 0 || ww >= S) continue;
          x2 += xr[j * P + hh * S + ww] * c3w[((c * 8 + j) * 3 + dy) * 3 + dx];
        }
      }
    }
    float fin = (a + x2) * (bng[c] * binv) + bnb[c];
    crout[((size_t)b * N_TOK + tok_off + p) * 8 + c] = fmaxf(fin, 0.f);
  }
}

// ---------------- 7/8: bf16 MFMA GEMM, 128x128 tile, BK=64, depth-4 ring + counted vmcnt ----
// Data layout & swizzle identical to verified R2 kernel; only the schedule changed.
// MODE 1: obf = bf16(gelu_exact(acc + bias))          (GEMM1)
// MODE 2: ofp = acc + bias + au_b + cr@au_w           (GEMM2 + adapter epilogue)
template <int MODE>
__global__ __launch_bounds__(256, 1) void k_gemm(
    const u16* __restrict__ A, const u16* __restrict__ Bt,
    const float* __restrict__ bias,
    u16* __restrict__ obf, float* __restrict__ ofp,
    const float* __restrict__ au_w, const float* __restrict__ au_b,
    const float* __restrict__ cr) {
  __shared__ __align__(16) u16 As[4][128 * 64];   // 64 KB
  __shared__ __align__(16) u16 Bs[4][128 * 64];   // 64 KB
  // T1: bijective XCD-chunked swizzle (nwg=1920, 1920%8==0, chunk=240)
  int orig = blockIdx.x;
  int wgid = (orig & 7) * 240 + (orig >> 3);
  int bm = wgid / 6, bn = wgid % 6;
  int m0 = bm * 128, n0 = bn * 128;
  int t = threadIdx.x, wave = t >> 6, lane = t & 63;
  int wr = wave >> 1, wc = wave & 1;
  const int l15 = lane & 15, l4 = lane >> 4;
  const int swz = (l15 & 7) << 4;

  // Pre-swizzled global stage sources (rule #21: linear LDS dest + inv-swz src + swz read)
  const char* srcA[4];
  const char* srcB[4];
  #pragma unroll
  for (int i = 0; i < 4; i++) {
    int b = i * 256 + t;
    int row = b >> 3;                       // 8 chunks per 128B row
    int colb = ((b & 7) << 4) ^ ((row & 7) << 4);
    srcA[i] = (const char*)A + (size_t)(m0 + row) * 1536 + colb;
    srcB[i] = (const char*)Bt + (size_t)(n0 + row) * 1536 + colb;
  }

  f32x4 acc[4][4];
  #pragma unroll
  for (int mi = 0; mi < 4; mi++)
    #pragma unroll
    for (int ni = 0; ni < 4; ni++) {
      f32x4 z = {0.f, 0.f, 0.f, 0.f};
      acc[mi][ni] = z;
    }

  auto STAGE = [&](int buf, int tile) {
    #pragma unroll
    for (int i = 0; i < 4; i++) {
      int basechunk = i * 256 + wave * 64;
      gll16(srcA[i] + 128 * tile, (void*)&As[buf][basechunk * 8]);
      gll16(srcB[i] + 128 * tile, (void*)&Bs[buf][basechunk * 8]);
    }
  };

  auto COMPUTE = [&](int buf) {
    const char* abase = (const char*)&As[buf][0];
    const char* bbase = (const char*)&Bs[buf][0];
    bf16x8 af[2][4], bf[2][4];
    #pragma unroll
    for (int kk = 0; kk < 2; kk++) {
      int cs = (kk * 64 + l4 * 16) ^ swz;
      #pragma unroll
      for (int mi = 0; mi < 4; mi++) {
        int R = wr * 64 + mi * 16 + l15;
        af[kk][mi] = *reinterpret_cast<const bf16x8*>(abase + R * 128 + cs);
      }
      #pragma unroll
      for (int ni = 0; ni < 4; ni++) {
        int R = wc * 64 + ni * 16 + l15;
        bf[kk][ni] = *reinterpret_cast<const bf16x8*>(bbase + R * 128 + cs);
      }
    }
    #pragma unroll
    for (int kk = 0; kk < 2; kk++)
      #pragma unroll
      for (int mi = 0; mi < 4; mi++)
        #pragma unroll
        for (int ni = 0; ni < 4; ni++)
          acc[mi][ni] = __builtin_amdgcn_mfma_f32_16x16x32_bf16(af[kk][mi], bf[kk][ni],
                                                                acc[mi][ni], 0, 0, 0);
  };

  // Prologue: fill all 4 buffers (32 loads/thread in flight)
  STAGE(0, 0); STAGE(1, 1); STAGE(2, 2); STAGE(3, 3);
  // Main loop: counted vmcnt keeps 3 tiles in flight across barriers (T4)
  #pragma unroll
  for (int s = 0; s < 12; ++s) {
    if (s < 9)        asm volatile("s_waitcnt vmcnt(24)" ::: "memory");
    else if (s == 9)  asm volatile("s_waitcnt vmcnt(16)" ::: "memory");
    else if (s == 10) asm volatile("s_waitcnt vmcnt(8)" ::: "memory");
    else              asm volatile("s_waitcnt vmcnt(0)" ::: "memory");
    RAW_BARRIER();                       // tile s visible to all waves
    __builtin_amdgcn_sched_barrier(0);
    COMPUTE(s & 3);
    if (s < 8) {
      RAW_BARRIER();                     // all waves done reading buf s&3
      __builtin_amdgcn_sched_barrier(0);
      STAGE(s & 3, s + 4);               // overwrite freed buffer
    }
  }

  // epilogue: C/D layout col = lane&15, row = 4*(lane>>4)+reg
  #pragma unroll
  for (int mi = 0; mi < 4; mi++) {
    #pragma unroll
    for (int ni = 0; ni < 4; ni++) {
      int colg = n0 + wc * 64 + ni * 16 + l15;
      #pragma unroll
      for (int rg = 0; rg < 4; rg++) {
        int rowg = m0 + wr * 64 + mi * 16 + l4 * 4 + rg;
        float vv = acc[mi][ni][rg] + bias[colg];
        if constexpr (MODE == 1) {
          vv = 0.5f * vv * (1.f + erff(vv * 0.70710678118654752f));
          obf[(size_t)rowg * 768 + colg] = f2b(vv);
        } else {
          vv += au_b[colg];
          const float* crr = cr + (size_t)rowg * 8;
          #pragma unroll
          for (int j = 0; j < 8; j++) vv += crr[j] * au_w[j * 768 + colg];
          ofp[(size_t)rowg * 768 + colg] = vv;
        }
      }
    }
  }
}

// ---------------- launch ----------------
extern "C" void kernel_launch(void* const* d_in, const int* in_sizes, int n_in,
                              void* d_out, int out_size, void* d_ws, size_t ws_size,
                              hipStream_t stream) {
  const float* x        = (const float*)d_in[0];
  const float* am_lin_w = (const float*)d_in[1];
  const float* am_lin_b = (const float*)d_in[2];
  const float* am_qkv_w = (const float*)d_in[3];
  const float* am_qkv_b = (const float*)d_in[4];
  const float* am_proj_w= (const float*)d_in[5];
  const float* am_proj_b= (const float*)d_in[6];
  const float* am_end_w = (const float*)d_in[7];
  const float* am_end_b = (const float*)d_in[8];
  const float* am_ln_g  = (const float*)d_in[9];
  const float* am_ln_b  = (const float*)d_in[10];
  const float* ln2_g    = (const float*)d_in[11];
  const float* ln2_b    = (const float*)d_in[12];
  const float* fc1_w    = (const float*)d_in[13];
  const float* fc1_b    = (const float*)d_in[14];
  const float* fc2_w    = (const float*)d_in[15];
  const float* fc2_b    = (const float*)d_in[16];
  const float* ad_w     = (const float*)d_in[17];
  const float* ad_b     = (const float*)d_in[18];
  const float* au_w     = (const float*)d_in[19];
  const float* au_b     = (const float*)d_in[20];
  const float* b1_w     = (const float*)d_in[21];
  const float* b1_b     = (const float*)d_in[22];
  const float* b1_bn_g  = (const float*)d_in[23];
  const float* b1_bn_b  = (const float*)d_in[24];
  const float* b2_w     = (const float*)d_in[25];
  const float* b2_b     = (const float*)d_in[26];
  const float* b2_bn_g  = (const float*)d_in[27];
  const float* b2_bn_b  = (const float*)d_in[28];
  const float* sx_cw    = (const float*)d_in[29];
  const float* sx_cr_w  = (const float*)d_in[30];
  const float* sx_cr_b  = (const float*)d_in[31];
  const float* sx_ci_w  = (const float*)d_in[32];
  const float* sx_ci_b  = (const float*)d_in[33];
  const float* sx_bn1_g = (const float*)d_in[34];
  const float* sx_bn1_b = (const float*)d_in[35];
  const float* sx_bn2_g = (const float*)d_in[36];
  const float* sx_bn2_b = (const float*)d_in[37];
  const float* sz_cw    = (const float*)d_in[38];
  const float* sz_cr_w  = (const float*)d_in[39];
  const float* sz_cr_b  = (const float*)d_in[40];
  const float* sz_ci_w  = (const float*)d_in[41];
  const float* sz_ci_b  = (const float*)d_in[42];
  const float* sz_bn1_g = (const float*)d_in[43];
  const float* sz_bn1_b = (const float*)d_in[44];
  const float* sz_bn2_g = (const float*)d_in[45];
  const float* sz_bn2_b = (const float*)d_in[46];
  const float* c1_w     = (const float*)d_in[47];
  const float* c1_b     = (const float*)d_in[48];
  const float* c2_w     = (const float*)d_in[49];
  const float* c2_b     = (const float*)d_in[50];
  const float* c3_w     = (const float*)d_in[51];
  const float* c3_b     = (const float*)d_in[52];
  const float* c4_w     = (const float*)d_in[53];
  const float* c4_b     = (const float*)d_in[54];
  const float* bn_g     = (const float*)d_in[55];
  const float* bn_b     = (const float*)d_in[56];

  char* ws = (char*)d_ws;
  constexpr size_t H_OFF   = 0;                         // h bf16 [40960][768]
  constexpr size_t G1_OFF  = 62914560;                  // g1 bf16 [40960][768]
  constexpr size_t W1T_OFF = 125829120;                 // fc1_w^T bf16 [768][768]
  constexpr size_t W2T_OFF = W1T_OFF + 1179648;
  constexpr size_t YXA_OFF = W2T_OFF + 1179648;         // yxa f32 [40960][16]
  constexpr size_t AV_OFF  = YXA_OFF + 2621440;         // av f32 [40960][8]
  constexpr size_t CR_OFF  = AV_OFF + 1310720;          // cr f32 [40960][8]

  u16* h_ws    = (u16*)(ws + H_OFF);
  u16* g1_ws   = (u16*)(ws + G1_OFF);
  u16* w1t     = (u16*)(ws + W1T_OFF);
  u16* w2t     = (u16*)(ws + W2T_OFF);
  float* yxa_ws= (float*)(ws + YXA_OFF);
  float* av_ws = (float*)(ws + AV_OFF);
  float* cr_ws = (float*)(ws + CR_OFF);

  k_transpose_bf16<<<dim3(24, 24), dim3(32, 8), 0, stream>>>(fc1_w, w1t);
  k_transpose_bf16<<<dim3(24, 24), dim3(32, 8), 0, stream>>>(fc2_w, w2t);
  k_lin<<<640, 256, 0, stream>>>(x, am_lin_w, am_lin_b, ad_w, ad_b, yxa_ws);
  k_attn<<<1024, 320, 0, stream>>>(yxa_ws, am_qkv_w, am_qkv_b, av_ws);
  k_token_c<<<M_TOT, 256, 0, stream>>>(x, yxa_ws, av_ws, am_proj_w, am_proj_b,
                                       am_end_w, am_end_b, am_ln_g, am_ln_b,
                                       ln2_g, ln2_b, h_ws);
  k_adapter<8><<<128, 256, 0, stream>>>(yxa_ws, b2_w, b2_b, b2_bn_g, b2_bn_b, sz_cw,
                                        sz_cr_w, sz_cr_b, sz_ci_w, sz_ci_b,
                                        sz_bn1_g, sz_bn1_b, sz_bn2_g, sz_bn2_b,
                                        c2_w, c2_b, c4_w, c4_b, bn_g, bn_b, cr_ws, 0);
  k_adapter<16><<<128, 256, 0, stream>>>(yxa_ws, b1_w, b1_b, b1_bn_g, b1_bn_b, sx_cw,
                                         sx_cr_w, sx_cr_b, sx_ci_w, sx_ci_b,
                                         sx_bn1_g, sx_bn1_b, sx_bn2_g, sx_bn2_b,
                                         c1_w, c1_b, c3_w, c3_b, bn_g, bn_b, cr_ws, 64);
  k_gemm<1><<<1920, 256, 0, stream>>>(h_ws, w1t, fc1_b, g1_ws, nullptr, nullptr, nullptr, nullptr);
  k_gemm<2><<<1920, 256, 0, stream>>>(g1_ws, w2t, fc2_b, nullptr, (float*)d_out, au_w, au_b, cr_ws);
}